// Round 10
// baseline (31.186 us; speedup 1.0000x reference)
//
#include <hip/hip_runtime.h>

#define C_IN   8
#define CH     8
#define Hh     128
#define Ww     192
#define HW     (Hh*Ww)
#define NINST  128
#define NPAR   169
#define OH     256
#define OW     384
#define B      4             // owned source rows per block
#define RT     (B+1)         // computed rows (incl. bottom halo)
#define NRG    (Hh/B)        // 32 row groups

typedef float f32x2 __attribute__((ext_vector_type(2)));

// Param layout per instance (169 floats):
// w0: [0,80) (8x10 row-major) | w1: [80,144) (8x8) | w2: [144,152) (1x8)
// b0: [152,160) | b1: [160,168) | b2: [168]
//
// Output mapping (verified R3-R9): block with source rows [r0, r0+B] writes
// out rows [2r0+2, 2r0+2+2B); rg==0 adds rows {0,1}; rg==NRG-1 clips at 256.
//
// Codegen lessons: (1) __launch_bounds__ 2nd arg w caps VGPRs ~256/w; w>=4
// spills (R6/R7). (2) Row-batched restructure spills even at w=3 (R8). The
// monolithic 5-row body is spill-free at w=3 (R5/R9: VGPR 76-84).
// (3) R10: weights are block-uniform -> read via uniform pointer with
// compile-time offsets so the compiler emits s_load (SGPR, no LDS/VALU cost).

__global__ __launch_bounds__(192, 3)
void fused_maskhead_kernel(const float* __restrict__ feats,
                           const float* __restrict__ params,
                           const float* __restrict__ locs,
                           const int* __restrict__ im_inds,
                           const int* __restrict__ fpn,
                           float* __restrict__ out)
{
    __shared__ float sl[RT][Ww];

    const int rg   = blockIdx.x;    // 0..31
    const int inst = blockIdx.y;    // 0..127
    const int x    = threadIdx.x;   // 0..191 — one column per thread
    const int r0   = rg * B;

    const float* __restrict__ P = params + inst * NPAR;   // block-uniform

    const float ixv = locs[inst * 2 + 0];
    const float iyv = locs[inst * 2 + 1];
    const float inv_soi = 1.0f / (float)(64 << fpn[inst]);
    const float rx = (ixv - (float)(x * 8 + 4)) * inv_soi;
    const float* fb = feats + (size_t)im_inds[inst] * (C_IN * HW) + x;

    // feats for all RT rows -> 40 regs (issued early, latency overlaps)
    float f[RT][C_IN];
    float ry[RT];
    #pragma unroll
    for (int k = 0; k < RT; ++k) {
        const int sr = min(r0 + k, Hh - 1);
        ry[k] = (iyv - (float)(sr * 8 + 4)) * inv_soi;
        #pragma unroll
        for (int c = 0; c < C_IN; ++c)
            f[k][c] = fb[c * HW + sr * Ww];
    }

    // ---- layer 1 (10 -> 8); weights via scalar loads (block-uniform)
    float h1[RT][CH];
    #pragma unroll
    for (int o = 0; o < CH; ++o) {
        const float c0 = fmaf(P[o * 10 + 0], rx, P[152 + o]);   // rx term hoisted
        const float wy = P[o * 10 + 1];
        #pragma unroll
        for (int k = 0; k < RT; ++k) {
            float a = fmaf(wy, ry[k], c0);
            #pragma unroll
            for (int c = 0; c < C_IN; ++c)
                a = fmaf(P[o * 10 + 2 + c], f[k][c], a);
            h1[k][o] = fmaxf(a, 0.0f);
        }
    }

    // ---- layer 2 (8 -> 8)
    float h2[RT][CH];
    #pragma unroll
    for (int o = 0; o < CH; ++o) {
        const float bo = P[160 + o];
        #pragma unroll
        for (int k = 0; k < RT; ++k) {
            float a = bo;
            #pragma unroll
            for (int c = 0; c < CH; ++c)
                a = fmaf(P[80 + o * 8 + c], h1[k][c], a);
            h2[k][o] = fmaxf(a, 0.0f);
        }
    }

    // ---- layer 3 (8 -> 1) -> LDS logits tile
    #pragma unroll
    for (int k = 0; k < RT; ++k) {
        float z = P[168];
        #pragma unroll
        for (int c = 0; c < CH; ++c)
            z = fmaf(P[144 + c], h2[k][c], z);
        sl[k][x] = z;
    }

    __syncthreads();

    // ---- 2x aligned bilinear from LDS tile, nontemporal f32x2 stores
    f32x2* outf2 = (f32x2*)out;
    const int xm1 = max(x - 1, 0);
    const int jlo = (rg == 0) ? -2 : 0;
    const int jhi = (rg == NRG - 1) ? 2 * B - 2 : 2 * B;

    #pragma unroll 4
    for (int jj = jlo; jj < jhi; ++jj) {
        const int oy  = 2 * r0 + 2 + jj;
        const int ay  = max(oy - 1, 0);
        const int y0l = (ay >> 1) - r0;            // 0..B
        const int y1l = min(y0l + 1, B);           // clamp only when fy==0
        const float fy = (ay & 1) ? 0.5f : 0.0f;

        const float t01 = sl[y0l][x];
        const float t00 = sl[y0l][xm1];
        const float t11 = sl[y1l][x];
        const float t10 = sl[y1l][xm1];

        const float rma = fmaf(fy, t10 - t00, t00);
        const float rmb = fmaf(fy, t11 - t01, t01);

        f32x2 v;
        v.x = 0.5f * (rma + rmb);
        v.y = rmb;
        __builtin_nontemporal_store(v, &outf2[((size_t)inst * OH + oy) * (OW / 2) + x]);
    }
}

extern "C" void kernel_launch(void* const* d_in, const int* in_sizes, int n_in,
                              void* d_out, int out_size, void* d_ws, size_t ws_size,
                              hipStream_t stream) {
    const float* feats  = (const float*)d_in[0];
    const float* params = (const float*)d_in[1];
    const float* locs   = (const float*)d_in[2];
    const int*   im     = (const int*)d_in[3];
    const int*   fpn    = (const int*)d_in[4];
    float* out = (float*)d_out;

    dim3 grid(NRG, NINST);   // 32 x 128 = 4096 blocks
    fused_maskhead_kernel<<<grid, 192, 0, stream>>>(feats, params, locs, im, fpn, out);
}

// Round 11
// 28.301 us; speedup vs baseline: 1.1019x; 1.1019x over previous
//
#include <hip/hip_runtime.h>

#define C_IN   8
#define CH     8
#define Hh     128
#define Ww     192
#define HW     (Hh*Ww)
#define NINST  128
#define NPAR   169
#define OH     256
#define OW     384
#define B      4             // owned source rows per block
#define RT     (B+1)         // computed rows (incl. bottom halo)
#define NRG    (Hh/B)        // 32 row groups

typedef float f32x2 __attribute__((ext_vector_type(2)));
typedef float f32x4 __attribute__((ext_vector_type(4)));

__device__ __forceinline__ f32x2 pk2(float s) { f32x2 r; r.x = s; r.y = s; return r; }

// Packed LDS weight layout (16B-aligned, 192 floats):
//   [0,96):   w0 as [8][12] (10 used + 2 pad)
//   [96,160): w1 as [8][8]
//   [160,168): w2[8]
//   [168,176): b0[8]  [176,184): b1[8]  [184]: b2
//
// Output mapping (verified R3-R10): block with source rows [r0, r0+B] writes
// out rows [2r0+2, 2r0+2+2B); rg==0 adds rows {0,1}; rg==NRG-1 clips at 256.
//
// Codegen lessons: (1) __launch_bounds__ 2nd arg w caps VGPRs ~256/w; w>=4
// spills (R6/R7). (2) Row-batched restructure spills even at w=3 (R8).
// (3) Scalar s_load weights regress (R10: SGPR pressure -> reloads in loop).
// (4) This round: rows paired as f32x2 so mul+add contracts to v_pk_fma_f32
//     (fp32 peak 157 TF = packed rate; halves VALU issue count of the MLP).

__global__ __launch_bounds__(192, 3)
void fused_maskhead_kernel(const float* __restrict__ feats,
                           const float* __restrict__ params,
                           const float* __restrict__ locs,
                           const int* __restrict__ im_inds,
                           const int* __restrict__ fpn,
                           float* __restrict__ out)
{
    __shared__ __align__(16) float sw[192];
    __shared__ float sl[RT][Ww];

    const int rg   = blockIdx.x;    // 0..31
    const int inst = blockIdx.y;    // 0..127
    const int x    = threadIdx.x;   // 0..191 — one column per thread
    const int r0   = rg * B;        // <= 124, so rows r0..r0+3 never clamp

    // stage + repack params (coalesced global read, remapped LDS write)
    if (x < NPAR) {
        const int r = x;
        int dst;
        if (r < 80)       { const int o = r / 10; dst = o * 12 + (r - o * 10); }
        else if (r < 144) dst = 96  + (r - 80);
        else if (r < 152) dst = 160 + (r - 144);
        else if (r < 160) dst = 168 + (r - 152);
        else if (r < 168) dst = 176 + (r - 160);
        else              dst = 184;
        sw[dst] = params[inst * NPAR + r];
    }

    const float ixv = locs[inst * 2 + 0];
    const float iyv = locs[inst * 2 + 1];
    const float inv_soi = 1.0f / (float)(64 << fpn[inst]);
    const float rx = (ixv - (float)(x * 8 + 4)) * inv_soi;
    const float* fb = feats + (size_t)im_inds[inst] * (C_IN * HW) + x;
    const int sr4 = min(r0 + 4, Hh - 1);

    // relative-y coords: rows paired {0,1},{2,3}; row 4 scalar
    f32x2 ry2[2];
    ry2[0].x = (iyv - (float)((r0 + 0) * 8 + 4)) * inv_soi;
    ry2[0].y = (iyv - (float)((r0 + 1) * 8 + 4)) * inv_soi;
    ry2[1].x = (iyv - (float)((r0 + 2) * 8 + 4)) * inv_soi;
    ry2[1].y = (iyv - (float)((r0 + 3) * 8 + 4)) * inv_soi;
    const float ry4 = (iyv - (float)(sr4 * 8 + 4)) * inv_soi;

    // feats: issued early, latency overlaps the LDS staging wait
    f32x2 f2[2][C_IN];
    float f4[C_IN];
    #pragma unroll
    for (int c = 0; c < C_IN; ++c) {
        const float* fc = fb + c * HW;
        f2[0][c].x = fc[(r0 + 0) * Ww];
        f2[0][c].y = fc[(r0 + 1) * Ww];
        f2[1][c].x = fc[(r0 + 2) * Ww];
        f2[1][c].y = fc[(r0 + 3) * Ww];
        f4[c]      = fc[sr4 * Ww];
    }

    __syncthreads();

    // ---- layer 1 (10 -> 8), pk-paired rows
    f32x2 h1a[CH], h1b[CH];
    float h1s[CH];
    #pragma unroll
    for (int o = 0; o < CH; ++o) {
        const f32x4 wa = *(const f32x4*)(sw + o * 12 + 0);
        const f32x4 wb = *(const f32x4*)(sw + o * 12 + 4);
        const f32x4 wc = *(const f32x4*)(sw + o * 12 + 8);   // .z/.w pad
        const float c0 = fmaf(wa.x, rx, sw[168 + o]);        // rx term hoisted
        const float wv[C_IN] = {wa.z, wa.w, wb.x, wb.y, wb.z, wb.w, wc.x, wc.y};

        f32x2 a0 = pk2(wa.y) * ry2[0] + pk2(c0);
        f32x2 a1 = pk2(wa.y) * ry2[1] + pk2(c0);
        float a4 = fmaf(wa.y, ry4, c0);
        #pragma unroll
        for (int c = 0; c < C_IN; ++c) {
            a0 = pk2(wv[c]) * f2[0][c] + a0;
            a1 = pk2(wv[c]) * f2[1][c] + a1;
            a4 = fmaf(wv[c], f4[c], a4);
        }
        h1a[o].x = fmaxf(a0.x, 0.0f);  h1a[o].y = fmaxf(a0.y, 0.0f);
        h1b[o].x = fmaxf(a1.x, 0.0f);  h1b[o].y = fmaxf(a1.y, 0.0f);
        h1s[o]   = fmaxf(a4, 0.0f);
    }

    // ---- layer 2 (8 -> 8)
    f32x2 h2a[CH], h2b[CH];
    float h2s[CH];
    #pragma unroll
    for (int o = 0; o < CH; ++o) {
        const f32x4 wa = *(const f32x4*)(sw + 96 + o * 8 + 0);
        const f32x4 wb = *(const f32x4*)(sw + 96 + o * 8 + 4);
        const float bo = sw[176 + o];
        const float wv[CH] = {wa.x, wa.y, wa.z, wa.w, wb.x, wb.y, wb.z, wb.w};

        f32x2 a0 = pk2(bo);
        f32x2 a1 = pk2(bo);
        float a4 = bo;
        #pragma unroll
        for (int c = 0; c < CH; ++c) {
            a0 = pk2(wv[c]) * h1a[c] + a0;
            a1 = pk2(wv[c]) * h1b[c] + a1;
            a4 = fmaf(wv[c], h1s[c], a4);
        }
        h2a[o].x = fmaxf(a0.x, 0.0f);  h2a[o].y = fmaxf(a0.y, 0.0f);
        h2b[o].x = fmaxf(a1.x, 0.0f);  h2b[o].y = fmaxf(a1.y, 0.0f);
        h2s[o]   = fmaxf(a4, 0.0f);
    }

    // ---- layer 3 (8 -> 1) -> LDS logits tile
    {
        const f32x4 wa = *(const f32x4*)(sw + 160);
        const f32x4 wb = *(const f32x4*)(sw + 164);
        const float bo = sw[184];
        const float wv[CH] = {wa.x, wa.y, wa.z, wa.w, wb.x, wb.y, wb.z, wb.w};

        f32x2 z0 = pk2(bo);
        f32x2 z1 = pk2(bo);
        float z4 = bo;
        #pragma unroll
        for (int c = 0; c < CH; ++c) {
            z0 = pk2(wv[c]) * h2a[c] + z0;
            z1 = pk2(wv[c]) * h2b[c] + z1;
            z4 = fmaf(wv[c], h2s[c], z4);
        }
        sl[0][x] = z0.x;
        sl[1][x] = z0.y;
        sl[2][x] = z1.x;
        sl[3][x] = z1.y;
        sl[4][x] = z4;
    }

    __syncthreads();

    // ---- 2x aligned bilinear from LDS tile
    f32x2* outf2 = (f32x2*)out;
    const int xm1 = max(x - 1, 0);
    const int jlo = (rg == 0) ? -2 : 0;
    const int jhi = (rg == NRG - 1) ? 2 * B - 2 : 2 * B;

    #pragma unroll 4
    for (int jj = jlo; jj < jhi; ++jj) {
        const int oy  = 2 * r0 + 2 + jj;
        const int ay  = max(oy - 1, 0);
        const int y0l = (ay >> 1) - r0;            // 0..B
        const int y1l = min(y0l + 1, B);           // clamp only when fy==0
        const float fy = (ay & 1) ? 0.5f : 0.0f;

        const float t01 = sl[y0l][x];
        const float t00 = sl[y0l][xm1];
        const float t11 = sl[y1l][x];
        const float t10 = sl[y1l][xm1];

        const float rma = fmaf(fy, t10 - t00, t00);
        const float rmb = fmaf(fy, t11 - t01, t01);

        f32x2 v;
        v.x = 0.5f * (rma + rmb);
        v.y = rmb;
        outf2[((size_t)inst * OH + oy) * (OW / 2) + x] = v;
    }
}

extern "C" void kernel_launch(void* const* d_in, const int* in_sizes, int n_in,
                              void* d_out, int out_size, void* d_ws, size_t ws_size,
                              hipStream_t stream) {
    const float* feats  = (const float*)d_in[0];
    const float* params = (const float*)d_in[1];
    const float* locs   = (const float*)d_in[2];
    const int*   im     = (const int*)d_in[3];
    const int*   fpn    = (const int*)d_in[4];
    float* out = (float*)d_out;

    dim3 grid(NRG, NINST);   // 32 x 128 = 4096 blocks
    fused_maskhead_kernel<<<grid, 192, 0, stream>>>(feats, params, locs, im, fpn, out);
}